// Round 19
// baseline (185.367 us; speedup 1.0000x reference)
//
#include <hip/hip_runtime.h>

// CAMixer agent-attention, fused per-window (8x8).  v19 = v18 + two latency nits:
//  - G1's 24-u16 xw B-gather hoisted into G0's phase (XWS immutable after P0 bar;
//    gather hides under G0's MFMA stream, crosses the barrier in registers).
//  - launch_bounds(256,6): LDS 25,088*6 = 147KB fits; VGPR budget ample.
//  Bit-identical numerics.
//
// Algebra (exact refactor, verified round 1):
//   agent   = conv(pool(x), Wq)
//   k-logit[p][l] = xw[l]·gk[p] + bkd[p],  gk = xp @ Mk + bk2,  Mk = Wq^T Wk
//   q-logit[l][p] = xw[l]·gq[p] + bqd[p],  gq = xp @ Mq + bq2,  Mq = Wq^T Wq
//   agent_v = (a_attn @ xw) @ Wv^T + bv
//
// MFMA conventions (verified v5-v18):
//   A-frag: lane = row + 16*kblk holds A[row][ks*32 + kblk*8 + j], j=0..7
//   B-frag: lane = col + 16*kblk holds B[ks*32 + kblk*8 + j][col]
//   C-frag: col = lane&15, row = (lane>>4)*4 + reg
//
// XWS layout (v7-proven): element (c,l) at byte c*128 + ((l*2) ^ ((c&7)<<4))

constexpr int C_   = 96;
constexpr int Wimg = 192;
constexpr int HWp  = 192 * 192;
constexpr int NWIN = 24;
constexpr int Pp   = 7;

typedef __attribute__((ext_vector_type(8))) __bf16 bf16x8;
typedef __attribute__((ext_vector_type(4))) __bf16 bf16x4;
typedef __attribute__((ext_vector_type(8))) short  short8;
typedef __attribute__((ext_vector_type(4))) float  f32x4;
union frag_u { short8 s; bf16x8 b; };

// ---- LDS byte offsets (total 25,024 B) ----
constexpr int XWS   = 0;        // xw bf16 [96][64], 128B rows, XOR-swizzled (12,288)
constexpr int RA    = 12288;    // 4,224: xp hi/lo [8][100] -> Lraw[8][66]f32 -> xv hi/lo
constexpr int XPH   = RA;
constexpr int XPL   = RA + 1600;
constexpr int LRAW  = RA;
constexpr int RB    = 16512;    // 6,400: gkq hi/lo [16][100] -> attn(4x1KB)
constexpr int GKQH  = RB;
constexpr int GKQL  = RB + 3200;
constexpr int QATH  = 22912;    // qat hi [64][16B]
constexpr int QATL  = 23936;    // qat lo [64][16B]
constexpr int BIAS  = 24960;    // f32[16]
constexpr int SMEMB = 25024;

// ---- ws offsets ----
// float idx: Mk 0, Mq 9216, uk 18432, uq 18528, bk2 18624, bq2 18720, scal 18816
constexpr int WS_FRAG_BYTE = 18944 * 4;                 // Mext frags: 84 slots x 1KB
constexpr int WS_WV_BYTE   = WS_FRAG_BYTE + 84 * 1024;  // Wv frags: 36 slots x 1KB

// ---------------- helpers ----------------

__device__ __forceinline__ void bar() {
    asm volatile("s_waitcnt lgkmcnt(0)" ::: "memory");
    __builtin_amdgcn_s_barrier();
}

__device__ __forceinline__ short8 xws_fragA(const unsigned char* S, int mt, int ks, int lane) {
    const int c  = mt * 16 + (lane & 15);
    const int l2 = ks * 64 + ((lane >> 4) << 4);
    return *reinterpret_cast<const short8*>(S + XWS + c * 128 + (l2 ^ ((c & 7) << 4)));
}

// pack a C-frag (4 consecutive columns) into one b64 hi + one b64 lo write
__device__ __forceinline__ void pack_hilo4(unsigned char* S, int hi_off, int lo_off,
                                           const f32x4 acc) {
    bf16x4 h, l;
    #pragma unroll
    for (int i = 0; i < 4; ++i) {
        h[i] = (__bf16)acc[i];
        l[i] = (__bf16)(acc[i] - (float)h[i]);
    }
    *reinterpret_cast<bf16x4*>(S + hi_off) = h;
    *reinterpret_cast<bf16x4*>(S + lo_off) = l;
}

// ---------------- precompute (weights only; mats+vecs merged, v11 patterns) ----------------

__global__ void precompute_mv(const float* __restrict__ Wq,
                              const float* __restrict__ Wk,
                              const float* __restrict__ bq,
                              const float* __restrict__ bk,
                              float* __restrict__ Mk,  float* __restrict__ Mq,
                              float* __restrict__ uk,  float* __restrict__ uq,
                              float* __restrict__ bk2, float* __restrict__ bq2,
                              float* __restrict__ scal)
{
    const int bid = blockIdx.x;
    if (bid < 96) {
        const int c  = bid;
        const int cp = threadIdx.x;
        float ak = 0.f, aq = 0.f;
        for (int a = 0; a < C_; ++a) {
            const float wq = Wq[a * C_ + c];
            ak = fmaf(wq, Wk[a * C_ + cp], ak);
            aq = fmaf(wq, Wq[a * C_ + cp], aq);
        }
        Mk[c * C_ + cp] = ak;
        Mq[c * C_ + cp] = aq;
    } else {
        const int c = threadIdx.x;
        float a_uk = 0.f, a_uq = 0.f, a_bk2 = 0.f, a_bq2 = 0.f;
        for (int a = 0; a < C_; ++a) {
            const float wqc = Wq[a * C_ + c];
            a_uk  = fmaf(wqc, bk[a], a_uk);
            a_uq  = fmaf(wqc, bq[a], a_uq);
            a_bk2 = fmaf(bq[a], Wk[a * C_ + c], a_bk2);
            a_bq2 = fmaf(bq[a], Wq[a * C_ + c], a_bq2);
        }
        uk[c] = a_uk; uq[c] = a_uq; bk2[c] = a_bk2; bq2[c] = a_bq2;
        if (c == 0) {
            float sk = 0.f, sq = 0.f;
            for (int a = 0; a < C_; ++a) { sk += bq[a] * bk[a]; sq += bq[a] * bq[a]; }
            scal[0] = sk; scal[1] = sq;
        }
    }
}

// frag tables: bid<84: Mext B-frags slot=((mat*7+nt)*3+ks)*2+hl; else Wv A-frags.
__global__ void precompute_frags(const float* __restrict__ ws,
                                 const float* __restrict__ Wv,
                                 unsigned char* __restrict__ wsb)
{
    const int bid = blockIdx.x, lane = threadIdx.x;
    short8 o;
    if (bid < 84) {
        const int hl = bid & 1, ks = (bid >> 1) % 3, nt = (bid / 6) % 7, mat = bid / 42;
        const float* M = ws + (mat ? 9216 : 0);
        const float* u = ws + (mat ? 18528 : 18432);
        const int col = nt * 16 + (lane & 15);
        #pragma unroll
        for (int j = 0; j < 8; ++j) {
            const int k = ks * 32 + (lane >> 4) * 8 + j;
            const float raw = (col < 96) ? M[k * 96 + col] : ((col == 96) ? u[k] : 0.f);
            const __bf16 hi = (__bf16)raw;
            union { __bf16 h; short s; } cv;
            cv.h = hl ? (__bf16)(raw - (float)hi) : hi;
            o[j] = cv.s;
        }
        *reinterpret_cast<short8*>(wsb + WS_FRAG_BYTE + bid * 1024 + lane * 16) = o;
    } else {
        const int wb = bid - 84;
        const int hl = wb & 1, ks = (wb >> 1) % 3, mt = wb / 6;
        const int row = mt * 16 + (lane & 15);
        #pragma unroll
        for (int j = 0; j < 8; ++j) {
            const int c = ks * 32 + (lane >> 4) * 8 + j;
            const float raw = Wv[row * 96 + c];
            const __bf16 hi = (__bf16)raw;
            union { __bf16 h; short s; } cv;
            cv.h = hl ? (__bf16)(raw - (float)hi) : hi;
            o[j] = cv.s;
        }
        *reinterpret_cast<short8*>(wsb + WS_WV_BYTE + wb * 1024 + lane * 16) = o;
    }
}

#define LOADPAIR(dstH, dstL, tab, slot_h) do {                                               \
    (dstH).s = *reinterpret_cast<const short8*>((tab) + (slot_h) * 1024 + (lane << 4));      \
    (dstL).s = *reinterpret_cast<const short8*>((tab) + ((slot_h) + 1) * 1024 + (lane << 4));\
} while (0)

// ---------------- main fused kernel ----------------

__global__ __launch_bounds__(256, 6) void camixer_main(
    const float* __restrict__ x,
    const float* __restrict__ bv,
    const float* __restrict__ bk2,
    const float* __restrict__ bq2,
    const float* __restrict__ scal,
    const unsigned char* __restrict__ mfrag,
    const unsigned char* __restrict__ wvfrag,
    float* __restrict__ out)
{
    __shared__ __align__(16) unsigned char S[SMEMB];
    float* Lraw   = (float*)(S + LRAW);  // [8][66] (k rows only)
    float* bias16 = (float*)(S + BIAS);  // [16]

    const int t = threadIdx.x;
    const int lane = t & 63, w = t >> 6;
    const int wid = ((blockIdx.x & 7) * 576) + (blockIdx.x >> 3);  // bijective XCD swizzle
    const int b  = wid / (NWIN * NWIN);
    const int r  = wid % (NWIN * NWIN);
    const int h0 = (r / NWIN) * 8;
    const int w0 = (r % NWIN) * 8;
    const int base = b * C_ * HWp + h0 * Wimg + w0;
    const float scal0 = scal[0], scal1 = scal[1];
    const short8 zero8 = {0, 0, 0, 0, 0, 0, 0, 0};

    // ---- prefetch G0 tile tt=w (A-operand Mext^T frags): under P0 + G_P ----
    frag_u B0h[3], B0l[3];
    LOADPAIR(B0h[0], B0l[0], mfrag, (w * 3 + 0) * 2);
    LOADPAIR(B0h[1], B0l[1], mfrag, (w * 3 + 1) * 2);
    LOADPAIR(B0h[2], B0l[2], mfrag, (w * 3 + 2) * 2);

    // ---- P0: x window -> bf16 XOR-swizzled row-major (single copy) ----
    {
        const float4* x4 = reinterpret_cast<const float4*>(x);
        #pragma unroll
        for (int rr = 0; rr < 2; ++rr) {
            const int idx = t + (rr << 8);          // 384 = 24 c4 x 8 dh x 2 dw4
            if (idx < 384) {
                const int dw4 = idx & 1;
                const int dh  = (idx >> 1) & 7;
                const int c4  = idx >> 4;
                const int c0 = c4 * 4, l0 = dh * 8 + dw4 * 4;
                #pragma unroll
                for (int j = 0; j < 4; ++j) {
                    const int c = c0 + j;
                    const float4 v = x4[(base + c * HWp + dh * Wimg + dw4 * 4) >> 2];
                    bf16x4 d = {(__bf16)v.x, (__bf16)v.y, (__bf16)v.z, (__bf16)v.w};
                    *reinterpret_cast<bf16x4*>(S + XWS + c * 128 + ((l0 * 2) ^ ((c & 7) << 4))) = d;
                }
            }
        }
    }
    bar();

    // ---- G_P (MFMA, swapped): xp^T-tiles = xw(A) @ P(B); out[c][p], packed b64 writes ----
    {
        frag_u PBh[2], PBl[2];                       // B-frag of P: lane = p + 16*kblk
        {
            const int p = lane & 15;
            const __bf16 PH = (__bf16)0.1f;
            const __bf16 PL = (__bf16)(0.1f - (float)PH);
            const int sp = (p < 7) ? ((p << 6) / 7) : 1000;
            #pragma unroll
            for (int ks = 0; ks < 2; ++ks)
                #pragma unroll
                for (int j = 0; j < 8; ++j) {
                    const int l = ks * 32 + (lane >> 4) * 8 + j;
                    const bool in = (l >= sp) && (l < sp + 10);
                    PBh[ks].b[j] = in ? PH : (__bf16)0.f;
                    PBl[ks].b[j] = in ? PL : (__bf16)0.f;
                }
        }
        #pragma unroll
        for (int rnd = 0; rnd < 2; ++rnd) {
            const int mt = rnd ? (4 + w) : w;        // c-tile
            if (rnd == 0 || w < 2) {
                f32x4 acc = {0.f, 0.f, 0.f, 0.f};
                #pragma unroll
                for (int ks = 0; ks < 2; ++ks) {
                    frag_u A;
                    A.s = xws_fragA(S, mt, ks, lane);
                    acc = __builtin_amdgcn_mfma_f32_16x16x32_bf16(A.b, PBh[ks].b, acc, 0, 0, 0);
                    acc = __builtin_amdgcn_mfma_f32_16x16x32_bf16(A.b, PBl[ks].b, acc, 0, 0, 0);
                }
                const int p = lane & 15;             // out col
                if (p < 8) {
                    const int c0 = mt * 16 + (lane >> 4) * 4;
                    pack_hilo4(S, XPH + p * 200 + c0 * 2, XPL + p * 200 + c0 * 2, acc);
                }
            }
        }
    }
    bar();

    // ---- G0 (MFMA, swapped+pipelined) + hoisted G1 B-gather (xw immutable) ----
    frag_u G1B[3];                                   // G1's xw B-frags, cross barrier in regs
    {
        frag_u Bh[3], Bl[3];                         // B-frag of xp^T == A-frag of xp
        #pragma unroll
        for (int ks = 0; ks < 3; ++ks) {
            const int off = ((lane & 15) & 7) * 200 + (ks * 32 + (lane >> 4) * 8) * 2;
            Bh[ks].s = *reinterpret_cast<const short8*>(S + XPH + off);
            Bl[ks].s = *reinterpret_cast<const short8*>(S + XPL + off);
        }
        // hoisted gather: xw[c = ks*32 + kblk*8 + j][l = w*16 + lane&15]
        {
            const int l2 = (w * 16 + (lane & 15)) * 2;
            const int kb = (lane >> 4) << 10;
            #pragma unroll
            for (int j = 0; j < 8; ++j) {
                const int aj = kb + j * 128 + (l2 ^ (j << 4));
                G1B[0].b[j] = *reinterpret_cast<const __bf16*>(S + XWS + aj);
                G1B[1].b[j] = *reinterpret_cast<const __bf16*>(S + XWS + 4096 + aj);
                G1B[2].b[j] = *reinterpret_cast<const __bf16*>(S + XWS + 8192 + aj);
            }
        }

        #define G0TILE(TT, AH, AL) do {                                               \
            const int tt_ = (TT);                                                     \
            const int mat_ = (tt_ >= 7) ? 1 : 0;                                      \
            const int nt_  = tt_ - 7 * mat_;         /* c'-tile */                    \
            f32x4 acc = {0.f, 0.f, 0.f, 0.f};                                         \
            acc = __builtin_amdgcn_mfma_f32_16x16x32_bf16(AH[0].b, Bh[0].b, acc, 0,0,0); \
            acc = __builtin_amdgcn_mfma_f32_16x16x32_bf16(AL[0].b, Bh[0].b, acc, 0,0,0); \
            acc = __builtin_amdgcn_mfma_f32_16x16x32_bf16(AH[0].b, Bl[0].b, acc, 0,0,0); \
            acc = __builtin_amdgcn_mfma_f32_16x16x32_bf16(AH[1].b, Bh[1].b, acc, 0,0,0); \
            acc = __builtin_amdgcn_mfma_f32_16x16x32_bf16(AL[1].b, Bh[1].b, acc, 0,0,0); \
            acc = __builtin_amdgcn_mfma_f32_16x16x32_bf16(AH[1].b, Bl[1].b, acc, 0,0,0); \
            acc = __builtin_amdgcn_mfma_f32_16x16x32_bf16(AH[2].b, Bh[2].b, acc, 0,0,0); \
            acc = __builtin_amdgcn_mfma_f32_16x16x32_bf16(AL[2].b, Bh[2].b, acc, 0,0,0); \
            acc = __builtin_amdgcn_mfma_f32_16x16x32_bf16(AH[2].b, Bl[2].b, acc, 0,0,0); \
            const int p_ = lane & 15;                /* out col */                    \
            if (nt_ < 6) {                                                            \
                if (p_ < 8) {                                                         \
                    const int cp0_ = nt_ * 16 + (lane >> 4) * 4;                      \
                    const float4 b4_ = *reinterpret_cast<const float4*>(              \
                        (mat_ ? bq2 : bk2) + cp0_);                                   \
                    f32x4 av_;                                                        \
                    av_[0] = acc[0] + b4_.x; av_[1] = acc[1] + b4_.y;                 \
                    av_[2] = acc[2] + b4_.z; av_[3] = acc[3] + b4_.w;                 \
                    const int pr_ = p_ + 8 * mat_;                                    \
                    pack_hilo4(S, GKQH + pr_ * 200 + cp0_ * 2,                        \
                               GKQL + pr_ * 200 + cp0_ * 2, av_);                     \
                }                                                                     \
            } else if ((lane >> 4) == 0 && p_ < 8) {                                  \
                bias16[p_ + 8 * mat_] = acc[0];      /* row c'=96 = bias dot */       \
            }                                                                         \
        } while (0)

        frag_u B1h[3], B1l[3], B2h[3], B2l[3], B3h[3], B3l[3];
        LOADPAIR(B1h[0], B1l[0], mfrag, ((w + 4) * 3 + 0) * 2);
        LOADPAIR(B1h[1], B1l[1], mfrag, ((w + 4) * 3 + 1) * 2);
        LOADPAIR(B1h[2], B1l[2], mfrag, ((w + 4) * 3 + 2) * 2);
        G0TILE(w, B0h, B0l);
        LOADPAIR(B2h[0], B2l[0], mfrag, ((w + 8) * 3 + 0) * 2);
        LOADPAIR(B2h[1], B2l[1], mfrag, ((w + 8) * 3 + 1) * 2);
        LOADPAIR(B2h[2], B2l[2], mfrag, ((w + 8) * 3 + 2) * 2);
        G0TILE(w + 4, B1h, B1l);
        if (w < 2) {
            LOADPAIR(B3h[0], B3l[0], mfrag, ((w + 12) * 3 + 0) * 2);
            LOADPAIR(B3h[1], B3l[1], mfrag, ((w + 12) * 3 + 1) * 2);
            LOADPAIR(B3h[2], B3l[2], mfrag, ((w + 12) * 3 + 2) * 2);
        }
        G0TILE(w + 8, B2h, B2l);
        if (w < 2) G0TILE(w + 12, B3h, B3l);
        #undef G0TILE
    }
    bar();

    // ---- G1 (MFMA): logits; k rows -> Lraw, q-softmax in-register -> qat ----
    {
        frag_u Ah[3], Al[3];
        #pragma unroll
        for (int ks = 0; ks < 3; ++ks) {
            const int off = (lane & 15) * 200 + (ks * 32 + (lane >> 4) * 8) * 2;
            Ah[ks].s = *reinterpret_cast<const short8*>(S + GKQH + off);
            Al[ks].s = *reinterpret_cast<const short8*>(S + GKQL + off);
        }
        f32x4 acc = {0.f, 0.f, 0.f, 0.f};
        #pragma unroll
        for (int ks = 0; ks < 3; ++ks) {
            acc = __builtin_amdgcn_mfma_f32_16x16x32_bf16(Ah[ks].b, G1B[ks].b, acc, 0, 0, 0);
            acc = __builtin_amdgcn_mfma_f32_16x16x32_bf16(Al[ks].b, G1B[ks].b, acc, 0, 0, 0);
        }
        const int colL = w * 16 + (lane & 15);
        const int g = lane >> 4;
        if (g < 2) {
            #pragma unroll
            for (int rr = 0; rr < 4; ++rr) {
                const int pr = g * 4 + rr;
                Lraw[pr * 66 + colL] = acc[rr] + bias16[pr] + scal0;
            }
        } else {
            const bool isg3 = (g == 3);
            float v[4];
            #pragma unroll
            for (int rr = 0; rr < 4; ++rr)
                v[rr] = acc[rr] + bias16[8 + (g - 2) * 4 + rr] + scal1;
            float mymax = fmaxf(fmaxf(v[0], v[1]), isg3 ? v[2] : fmaxf(v[2], v[3]));
            const float omax = __shfl_xor(mymax, 16);
            const float mx = fmaxf(mymax, omax);
            float e[4];
            e[0] = __expf(v[0] - mx); e[1] = __expf(v[1] - mx); e[2] = __expf(v[2] - mx);
            e[3] = isg3 ? 0.f : __expf(v[3] - mx);
            float mysum = (e[0] + e[1]) + (e[2] + e[3]);
            const float osum = __shfl_xor(mysum, 16);
            const float inv = 1.f / (mysum + osum);
            float a[4], pa[4];
            #pragma unroll
            for (int rr = 0; rr < 4; ++rr) a[rr] = e[rr] * inv;
            #pragma unroll
            for (int rr = 0; rr < 4; ++rr) pa[rr] = __shfl_xor(a[rr], 16);
            if (!isg3) {
                frag_u qh, ql;
                #pragma unroll
                for (int p = 0; p < 4; ++p) {
                    const __bf16 hb = (__bf16)a[p];
                    qh.b[p] = hb; ql.b[p] = (__bf16)(a[p] - (float)hb);
                }
                #pragma unroll
                for (int p = 0; p < 4; ++p) {
                    const __bf16 hb = (__bf16)pa[p];     // pa[3] = 0 (partner e[3]=0)
                    qh.b[4 + p] = hb; ql.b[4 + p] = (__bf16)(pa[p] - (float)hb);
                }
                *reinterpret_cast<short8*>(S + QATH + colL * 16) = qh.s;
                *reinterpret_cast<short8*>(S + QATL + colL * 16) = ql.s;
            }
        }
    }
    bar();

    // ---- SM: k-softmax only (7 rows over 4 waves) -> attn frags ----
    {
        const int nrows = (w < 3) ? 2 : 1;
        #pragma unroll
        for (int rr = 0; rr < 2; ++rr) {
            if (rr < nrows) {
                const int pp = (w < 3) ? (w + 3 * rr) : 6;
                const float v = Lraw[pp * 66 + lane];
                float mx = v;
                #pragma unroll
                for (int off = 32; off; off >>= 1) mx = fmaxf(mx, __shfl_xor(mx, off));
                const float e = __expf(v - mx);
                float s = e;
                #pragma unroll
                for (int off = 32; off; off >>= 1) s += __shfl_xor(s, off);
                const float a = e / s;
                const __bf16 hb = (__bf16)a;
                const __bf16 lb = (__bf16)(a - (float)hb);
                const int ks = lane >> 5;
                const int off_b = ((pp + 16 * ((lane >> 3) & 3)) << 4) + ((lane & 7) << 1);
                *reinterpret_cast<__bf16*>(S + RB + (ks << 10) + off_b) = hb;
                *reinterpret_cast<__bf16*>(S + RB + ((2 + ks) << 10) + off_b) = lb;
            }
        }
    }
    bar();

    // ---- G2 (MFMA) + wvfrag prefetch: xv^T = xw(A) @ attn(B); packed b64 writes ----
    frag_u V0h[3], V0l[3], V1h[3], V1l[3];
    {
        LOADPAIR(V0h[0], V0l[0], wvfrag, (w * 3 + 0) * 2);
        LOADPAIR(V0h[1], V0l[1], wvfrag, (w * 3 + 1) * 2);
        LOADPAIR(V0h[2], V0l[2], wvfrag, (w * 3 + 2) * 2);
        if (w < 2) {
            LOADPAIR(V1h[0], V1l[0], wvfrag, ((4 + w) * 3 + 0) * 2);
            LOADPAIR(V1h[1], V1l[1], wvfrag, ((4 + w) * 3 + 1) * 2);
            LOADPAIR(V1h[2], V1l[2], wvfrag, ((4 + w) * 3 + 2) * 2);
        }

        frag_u Bh[2], Bl[2];
        #pragma unroll
        for (int ks = 0; ks < 2; ++ks) {
            Bh[ks].s = *reinterpret_cast<const short8*>(S + RB + (ks << 10) + (lane << 4));
            Bl[ks].s = *reinterpret_cast<const short8*>(S + RB + ((2 + ks) << 10) + (lane << 4));
        }
        const int mt0 = (w < 2) ? w * 2 : (w + 2);
        const int nmt = (w < 2) ? 2 : 1;
        for (int m = 0; m < nmt; ++m) {
            const int mt = mt0 + m;
            f32x4 acc = {0.f, 0.f, 0.f, 0.f};
            #pragma unroll
            for (int ks = 0; ks < 2; ++ks) {
                frag_u A;
                A.s = xws_fragA(S, mt, ks, lane);
                acc = __builtin_amdgcn_mfma_f32_16x16x32_bf16(A.b, Bh[ks].b, acc, 0, 0, 0);
                acc = __builtin_amdgcn_mfma_f32_16x16x32_bf16(A.b, Bl[ks].b, acc, 0, 0, 0);
            }
            const int p = lane & 15;
            if (p < 8) {                              // rows >=8 never read
                const int c0 = mt * 16 + (lane >> 4) * 4;
                pack_hilo4(S, XPH + p * 200 + c0 * 2, XPL + p * 200 + c0 * 2, acc);
            }
        }
    }
    bar();

    // ---- G3+P7 fused: av built in-register -> out (no av LDS, no final barrier) ----
    {
        const bool row7 = ((lane & 15) & 7) == 7;    // xv row 7 = garbage guard
        frag_u Ah[3], Al[3];                         // A-frag of xv: lane = p + 16kblk
        #pragma unroll
        for (int ks = 0; ks < 3; ++ks) {
            const int off = ((lane & 15) & 7) * 200 + (ks * 32 + (lane >> 4) * 8) * 2;
            Ah[ks].s = row7 ? zero8 : *reinterpret_cast<const short8*>(S + XPH + off);
            Al[ks].s = row7 ? zero8 : *reinterpret_cast<const short8*>(S + XPL + off);
        }

        frag_u PA0h, PA0l, PA1h, PA1l;               // P7 A-frags (av[o][p0..7])
        #define G3ACC(OT, VH, VL, DSTH, DSTL) do {                                    \
            f32x4 acc = {0.f, 0.f, 0.f, 0.f};                                         \
            acc = __builtin_amdgcn_mfma_f32_16x16x32_bf16(Ah[0].b, VH[0].b, acc, 0,0,0); \
            acc = __builtin_amdgcn_mfma_f32_16x16x32_bf16(Al[0].b, VH[0].b, acc, 0,0,0); \
            acc = __builtin_amdgcn_mfma_f32_16x16x32_bf16(Ah[0].b, VL[0].b, acc, 0,0,0); \
            acc = __builtin_amdgcn_mfma_f32_16x16x32_bf16(Ah[1].b, VH[1].b, acc, 0,0,0); \
            acc = __builtin_amdgcn_mfma_f32_16x16x32_bf16(Al[1].b, VH[1].b, acc, 0,0,0); \
            acc = __builtin_amdgcn_mfma_f32_16x16x32_bf16(Ah[1].b, VL[1].b, acc, 0,0,0); \
            acc = __builtin_amdgcn_mfma_f32_16x16x32_bf16(Ah[2].b, VH[2].b, acc, 0,0,0); \
            acc = __builtin_amdgcn_mfma_f32_16x16x32_bf16(Al[2].b, VH[2].b, acc, 0,0,0); \
            acc = __builtin_amdgcn_mfma_f32_16x16x32_bf16(Ah[2].b, VL[2].b, acc, 0,0,0); \
            float p47[4];                                                             \
            _Pragma("unroll")                                                         \
            for (int rr = 0; rr < 4; ++rr) p47[rr] = __shfl_xor(acc[rr], 16);         \
            if ((lane >> 4) == 0) {                                                   \
                const float bvo_ = bv[(OT) * 16 + (lane & 15)];                       \
                float vv[8] = {acc[0] + bvo_, acc[1] + bvo_, acc[2] + bvo_,           \
                               acc[3] + bvo_, p47[0] + bvo_, p47[1] + bvo_,           \
                               p47[2] + bvo_, p47[3] + bvo_};                         \
                _Pragma("unroll")                                                     \
                for (int j = 0; j < 8; ++j) {                                         \
                    const __bf16 hb = (__bf16)vv[j];                                  \
                    (DSTH).b[j] = hb;                                                 \
                    (DSTL).b[j] = (__bf16)(vv[j] - (float)hb);                        \
                }                                                                     \
            } else { (DSTH).s = zero8; (DSTL).s = zero8; }                            \
        } while (0)
        G3ACC(w, V0h, V0l, PA0h, PA0l);
        if (w < 2) G3ACC(4 + w, V1h, V1l, PA1h, PA1l);
        #undef G3ACC

        // P7: out^T[o][l] = av(A, in-reg) @ qat^T(B); each wave: own o-tiles, all l
        #pragma unroll
        for (int lt = 0; lt < 4; ++lt) {
            const int ll = lt * 16 + (lane & 15);
            frag_u Bh, Bl;
            if ((lane >> 4) == 0) {
                Bh.s = *reinterpret_cast<const short8*>(S + QATH + ll * 16);
                Bl.s = *reinterpret_cast<const short8*>(S + QATL + ll * 16);
            } else { Bh.s = zero8; Bl.s = zero8; }
            const int obase = b * C_ * HWp + (h0 + (ll >> 3)) * Wimg + w0 + (ll & 7);
            {
                f32x4 a0 = {0.f, 0.f, 0.f, 0.f};
                a0 = __builtin_amdgcn_mfma_f32_16x16x32_bf16(PA0h.b, Bh.b, a0, 0, 0, 0);
                a0 = __builtin_amdgcn_mfma_f32_16x16x32_bf16(PA0h.b, Bl.b, a0, 0, 0, 0);
                a0 = __builtin_amdgcn_mfma_f32_16x16x32_bf16(PA0l.b, Bh.b, a0, 0, 0, 0);
                #pragma unroll
                for (int rr = 0; rr < 4; ++rr) {
                    const int o = w * 16 + (lane >> 4) * 4 + rr;
                    out[obase + o * HWp] = a0[rr];
                }
            }
            if (w < 2) {
                f32x4 a1 = {0.f, 0.f, 0.f, 0.f};
                a1 = __builtin_amdgcn_mfma_f32_16x16x32_bf16(PA1h.b, Bh.b, a1, 0, 0, 0);
                a1 = __builtin_amdgcn_mfma_f32_16x16x32_bf16(PA1h.b, Bl.b, a1, 0, 0, 0);
                a1 = __builtin_amdgcn_mfma_f32_16x16x32_bf16(PA1l.b, Bh.b, a1, 0, 0, 0);
                #pragma unroll
                for (int rr = 0; rr < 4; ++rr) {
                    const int o = (4 + w) * 16 + (lane >> 4) * 4 + rr;
                    out[obase + o * HWp] = a1[rr];
                }
            }
        }
    }
}

// ---------------- launch ----------------

extern "C" void kernel_launch(void* const* d_in, const int* in_sizes, int n_in,
                              void* d_out, int out_size, void* d_ws, size_t ws_size,
                              hipStream_t stream)
{
    const float* x  = (const float*)d_in[0];
    const float* Wv = (const float*)d_in[1];
    const float* bv = (const float*)d_in[2];
    const float* Wq = (const float*)d_in[3];
    const float* bq = (const float*)d_in[4];
    const float* Wk = (const float*)d_in[5];
    const float* bk = (const float*)d_in[6];
    float* out = (float*)d_out;

    float* ws = (float*)d_ws;
    float* Mk   = ws;                 // 9216
    float* Mq   = ws + 9216;          // 9216
    float* uk   = ws + 18432;
    float* uq   = ws + 18528;
    float* bk2  = ws + 18624;
    float* bq2  = ws + 18720;
    float* scal = ws + 18816;
    unsigned char* wsb = (unsigned char*)d_ws;

    hipLaunchKernelGGL(precompute_mv, dim3(97), dim3(C_), 0, stream,
                       Wq, Wk, bq, bk, Mk, Mq, uk, uq, bk2, bq2, scal);
    hipLaunchKernelGGL(precompute_frags, dim3(120), dim3(64), 0, stream,
                       ws, Wv, wsb);
    hipLaunchKernelGGL(camixer_main, dim3(8 * NWIN * NWIN), dim3(256), 0, stream,
                       x, bv, bk2, bq2, scal,
                       wsb + WS_FRAG_BYTE, wsb + WS_WV_BYTE, out);
}

// Round 20
// 141.787 us; speedup vs baseline: 1.3074x; 1.3074x over previous
//
#include <hip/hip_runtime.h>

// CAMixer agent-attention, fused per-window (8x8).  v20 = v19 with the
// launch_bounds regression reverted: (256,6) forced VGPR=40 -> ~750MB scratch
// spill (v3's lesson repeated). Back to (256,5); G1-gather hoist + G3->P7
// fusion + swapped GEMMs kept. Bit-identical numerics.
//
// Algebra (exact refactor, verified round 1):
//   agent   = conv(pool(x), Wq)
//   k-logit[p][l] = xw[l]·gk[p] + bkd[p],  gk = xp @ Mk + bk2,  Mk = Wq^T Wk
//   q-logit[l][p] = xw[l]·gq[p] + bqd[p],  gq = xp @ Mq + bq2,  Mq = Wq^T Wq
//   agent_v = (a_attn @ xw) @ Wv^T + bv
//
// MFMA conventions (verified v5-v18):
//   A-frag: lane = row + 16*kblk holds A[row][ks*32 + kblk*8 + j], j=0..7
//   B-frag: lane = col + 16*kblk holds B[ks*32 + kblk*8 + j][col]
//   C-frag: col = lane&15, row = (lane>>4)*4 + reg
//
// XWS layout (v7-proven): element (c,l) at byte c*128 + ((l*2) ^ ((c&7)<<4))

constexpr int C_   = 96;
constexpr int Wimg = 192;
constexpr int HWp  = 192 * 192;
constexpr int NWIN = 24;
constexpr int Pp   = 7;

typedef __attribute__((ext_vector_type(8))) __bf16 bf16x8;
typedef __attribute__((ext_vector_type(4))) __bf16 bf16x4;
typedef __attribute__((ext_vector_type(8))) short  short8;
typedef __attribute__((ext_vector_type(4))) float  f32x4;
union frag_u { short8 s; bf16x8 b; };

// ---- LDS byte offsets (total 25,024 B) ----
constexpr int XWS   = 0;        // xw bf16 [96][64], 128B rows, XOR-swizzled (12,288)
constexpr int RA    = 12288;    // 4,224: xp hi/lo [8][100] -> Lraw[8][66]f32 -> xv hi/lo
constexpr int XPH   = RA;
constexpr int XPL   = RA + 1600;
constexpr int LRAW  = RA;
constexpr int RB    = 16512;    // 6,400: gkq hi/lo [16][100] -> attn(4x1KB)
constexpr int GKQH  = RB;
constexpr int GKQL  = RB + 3200;
constexpr int QATH  = 22912;    // qat hi [64][16B]
constexpr int QATL  = 23936;    // qat lo [64][16B]
constexpr int BIAS  = 24960;    // f32[16]
constexpr int SMEMB = 25024;

// ---- ws offsets ----
// float idx: Mk 0, Mq 9216, uk 18432, uq 18528, bk2 18624, bq2 18720, scal 18816
constexpr int WS_FRAG_BYTE = 18944 * 4;                 // Mext frags: 84 slots x 1KB
constexpr int WS_WV_BYTE   = WS_FRAG_BYTE + 84 * 1024;  // Wv frags: 36 slots x 1KB

// ---------------- helpers ----------------

__device__ __forceinline__ void bar() {
    asm volatile("s_waitcnt lgkmcnt(0)" ::: "memory");
    __builtin_amdgcn_s_barrier();
}

__device__ __forceinline__ short8 xws_fragA(const unsigned char* S, int mt, int ks, int lane) {
    const int c  = mt * 16 + (lane & 15);
    const int l2 = ks * 64 + ((lane >> 4) << 4);
    return *reinterpret_cast<const short8*>(S + XWS + c * 128 + (l2 ^ ((c & 7) << 4)));
}

// pack a C-frag (4 consecutive columns) into one b64 hi + one b64 lo write
__device__ __forceinline__ void pack_hilo4(unsigned char* S, int hi_off, int lo_off,
                                           const f32x4 acc) {
    bf16x4 h, l;
    #pragma unroll
    for (int i = 0; i < 4; ++i) {
        h[i] = (__bf16)acc[i];
        l[i] = (__bf16)(acc[i] - (float)h[i]);
    }
    *reinterpret_cast<bf16x4*>(S + hi_off) = h;
    *reinterpret_cast<bf16x4*>(S + lo_off) = l;
}

// ---------------- precompute (weights only; mats+vecs merged, v11 patterns) ----------------

__global__ void precompute_mv(const float* __restrict__ Wq,
                              const float* __restrict__ Wk,
                              const float* __restrict__ bq,
                              const float* __restrict__ bk,
                              float* __restrict__ Mk,  float* __restrict__ Mq,
                              float* __restrict__ uk,  float* __restrict__ uq,
                              float* __restrict__ bk2, float* __restrict__ bq2,
                              float* __restrict__ scal)
{
    const int bid = blockIdx.x;
    if (bid < 96) {
        const int c  = bid;
        const int cp = threadIdx.x;
        float ak = 0.f, aq = 0.f;
        for (int a = 0; a < C_; ++a) {
            const float wq = Wq[a * C_ + c];
            ak = fmaf(wq, Wk[a * C_ + cp], ak);
            aq = fmaf(wq, Wq[a * C_ + cp], aq);
        }
        Mk[c * C_ + cp] = ak;
        Mq[c * C_ + cp] = aq;
    } else {
        const int c = threadIdx.x;
        float a_uk = 0.f, a_uq = 0.f, a_bk2 = 0.f, a_bq2 = 0.f;
        for (int a = 0; a < C_; ++a) {
            const float wqc = Wq[a * C_ + c];
            a_uk  = fmaf(wqc, bk[a], a_uk);
            a_uq  = fmaf(wqc, bq[a], a_uq);
            a_bk2 = fmaf(bq[a], Wk[a * C_ + c], a_bk2);
            a_bq2 = fmaf(bq[a], Wq[a * C_ + c], a_bq2);
        }
        uk[c] = a_uk; uq[c] = a_uq; bk2[c] = a_bk2; bq2[c] = a_bq2;
        if (c == 0) {
            float sk = 0.f, sq = 0.f;
            for (int a = 0; a < C_; ++a) { sk += bq[a] * bk[a]; sq += bq[a] * bq[a]; }
            scal[0] = sk; scal[1] = sq;
        }
    }
}

// frag tables: bid<84: Mext B-frags slot=((mat*7+nt)*3+ks)*2+hl; else Wv A-frags.
__global__ void precompute_frags(const float* __restrict__ ws,
                                 const float* __restrict__ Wv,
                                 unsigned char* __restrict__ wsb)
{
    const int bid = blockIdx.x, lane = threadIdx.x;
    short8 o;
    if (bid < 84) {
        const int hl = bid & 1, ks = (bid >> 1) % 3, nt = (bid / 6) % 7, mat = bid / 42;
        const float* M = ws + (mat ? 9216 : 0);
        const float* u = ws + (mat ? 18528 : 18432);
        const int col = nt * 16 + (lane & 15);
        #pragma unroll
        for (int j = 0; j < 8; ++j) {
            const int k = ks * 32 + (lane >> 4) * 8 + j;
            const float raw = (col < 96) ? M[k * 96 + col] : ((col == 96) ? u[k] : 0.f);
            const __bf16 hi = (__bf16)raw;
            union { __bf16 h; short s; } cv;
            cv.h = hl ? (__bf16)(raw - (float)hi) : hi;
            o[j] = cv.s;
        }
        *reinterpret_cast<short8*>(wsb + WS_FRAG_BYTE + bid * 1024 + lane * 16) = o;
    } else {
        const int wb = bid - 84;
        const int hl = wb & 1, ks = (wb >> 1) % 3, mt = wb / 6;
        const int row = mt * 16 + (lane & 15);
        #pragma unroll
        for (int j = 0; j < 8; ++j) {
            const int c = ks * 32 + (lane >> 4) * 8 + j;
            const float raw = Wv[row * 96 + c];
            const __bf16 hi = (__bf16)raw;
            union { __bf16 h; short s; } cv;
            cv.h = hl ? (__bf16)(raw - (float)hi) : hi;
            o[j] = cv.s;
        }
        *reinterpret_cast<short8*>(wsb + WS_WV_BYTE + wb * 1024 + lane * 16) = o;
    }
}

#define LOADPAIR(dstH, dstL, tab, slot_h) do {                                               \
    (dstH).s = *reinterpret_cast<const short8*>((tab) + (slot_h) * 1024 + (lane << 4));      \
    (dstL).s = *reinterpret_cast<const short8*>((tab) + ((slot_h) + 1) * 1024 + (lane << 4));\
} while (0)

// ---------------- main fused kernel ----------------

__global__ __launch_bounds__(256, 5) void camixer_main(
    const float* __restrict__ x,
    const float* __restrict__ bv,
    const float* __restrict__ bk2,
    const float* __restrict__ bq2,
    const float* __restrict__ scal,
    const unsigned char* __restrict__ mfrag,
    const unsigned char* __restrict__ wvfrag,
    float* __restrict__ out)
{
    __shared__ __align__(16) unsigned char S[SMEMB];
    float* Lraw   = (float*)(S + LRAW);  // [8][66] (k rows only)
    float* bias16 = (float*)(S + BIAS);  // [16]

    const int t = threadIdx.x;
    const int lane = t & 63, w = t >> 6;
    const int wid = ((blockIdx.x & 7) * 576) + (blockIdx.x >> 3);  // bijective XCD swizzle
    const int b  = wid / (NWIN * NWIN);
    const int r  = wid % (NWIN * NWIN);
    const int h0 = (r / NWIN) * 8;
    const int w0 = (r % NWIN) * 8;
    const int base = b * C_ * HWp + h0 * Wimg + w0;
    const float scal0 = scal[0], scal1 = scal[1];
    const short8 zero8 = {0, 0, 0, 0, 0, 0, 0, 0};

    // ---- prefetch G0 tile tt=w (A-operand Mext^T frags): under P0 + G_P ----
    frag_u B0h[3], B0l[3];
    LOADPAIR(B0h[0], B0l[0], mfrag, (w * 3 + 0) * 2);
    LOADPAIR(B0h[1], B0l[1], mfrag, (w * 3 + 1) * 2);
    LOADPAIR(B0h[2], B0l[2], mfrag, (w * 3 + 2) * 2);

    // ---- P0: x window -> bf16 XOR-swizzled row-major (single copy) ----
    {
        const float4* x4 = reinterpret_cast<const float4*>(x);
        #pragma unroll
        for (int rr = 0; rr < 2; ++rr) {
            const int idx = t + (rr << 8);          // 384 = 24 c4 x 8 dh x 2 dw4
            if (idx < 384) {
                const int dw4 = idx & 1;
                const int dh  = (idx >> 1) & 7;
                const int c4  = idx >> 4;
                const int c0 = c4 * 4, l0 = dh * 8 + dw4 * 4;
                #pragma unroll
                for (int j = 0; j < 4; ++j) {
                    const int c = c0 + j;
                    const float4 v = x4[(base + c * HWp + dh * Wimg + dw4 * 4) >> 2];
                    bf16x4 d = {(__bf16)v.x, (__bf16)v.y, (__bf16)v.z, (__bf16)v.w};
                    *reinterpret_cast<bf16x4*>(S + XWS + c * 128 + ((l0 * 2) ^ ((c & 7) << 4))) = d;
                }
            }
        }
    }
    bar();

    // ---- G_P (MFMA, swapped): xp^T-tiles = xw(A) @ P(B); out[c][p], packed b64 writes ----
    {
        frag_u PBh[2], PBl[2];                       // B-frag of P: lane = p + 16*kblk
        {
            const int p = lane & 15;
            const __bf16 PH = (__bf16)0.1f;
            const __bf16 PL = (__bf16)(0.1f - (float)PH);
            const int sp = (p < 7) ? ((p << 6) / 7) : 1000;
            #pragma unroll
            for (int ks = 0; ks < 2; ++ks)
                #pragma unroll
                for (int j = 0; j < 8; ++j) {
                    const int l = ks * 32 + (lane >> 4) * 8 + j;
                    const bool in = (l >= sp) && (l < sp + 10);
                    PBh[ks].b[j] = in ? PH : (__bf16)0.f;
                    PBl[ks].b[j] = in ? PL : (__bf16)0.f;
                }
        }
        #pragma unroll
        for (int rnd = 0; rnd < 2; ++rnd) {
            const int mt = rnd ? (4 + w) : w;        // c-tile
            if (rnd == 0 || w < 2) {
                f32x4 acc = {0.f, 0.f, 0.f, 0.f};
                #pragma unroll
                for (int ks = 0; ks < 2; ++ks) {
                    frag_u A;
                    A.s = xws_fragA(S, mt, ks, lane);
                    acc = __builtin_amdgcn_mfma_f32_16x16x32_bf16(A.b, PBh[ks].b, acc, 0, 0, 0);
                    acc = __builtin_amdgcn_mfma_f32_16x16x32_bf16(A.b, PBl[ks].b, acc, 0, 0, 0);
                }
                const int p = lane & 15;             // out col
                if (p < 8) {
                    const int c0 = mt * 16 + (lane >> 4) * 4;
                    pack_hilo4(S, XPH + p * 200 + c0 * 2, XPL + p * 200 + c0 * 2, acc);
                }
            }
        }
    }
    bar();

    // ---- G0 (MFMA, swapped+pipelined) + hoisted G1 B-gather (xw immutable) ----
    frag_u G1B[3];                                   // G1's xw B-frags, cross barrier in regs
    {
        frag_u Bh[3], Bl[3];                         // B-frag of xp^T == A-frag of xp
        #pragma unroll
        for (int ks = 0; ks < 3; ++ks) {
            const int off = ((lane & 15) & 7) * 200 + (ks * 32 + (lane >> 4) * 8) * 2;
            Bh[ks].s = *reinterpret_cast<const short8*>(S + XPH + off);
            Bl[ks].s = *reinterpret_cast<const short8*>(S + XPL + off);
        }
        // hoisted gather: xw[c = ks*32 + kblk*8 + j][l = w*16 + lane&15]
        {
            const int l2 = (w * 16 + (lane & 15)) * 2;
            const int kb = (lane >> 4) << 10;
            #pragma unroll
            for (int j = 0; j < 8; ++j) {
                const int aj = kb + j * 128 + (l2 ^ (j << 4));
                G1B[0].b[j] = *reinterpret_cast<const __bf16*>(S + XWS + aj);
                G1B[1].b[j] = *reinterpret_cast<const __bf16*>(S + XWS + 4096 + aj);
                G1B[2].b[j] = *reinterpret_cast<const __bf16*>(S + XWS + 8192 + aj);
            }
        }

        #define G0TILE(TT, AH, AL) do {                                               \
            const int tt_ = (TT);                                                     \
            const int mat_ = (tt_ >= 7) ? 1 : 0;                                      \
            const int nt_  = tt_ - 7 * mat_;         /* c'-tile */                    \
            f32x4 acc = {0.f, 0.f, 0.f, 0.f};                                         \
            acc = __builtin_amdgcn_mfma_f32_16x16x32_bf16(AH[0].b, Bh[0].b, acc, 0,0,0); \
            acc = __builtin_amdgcn_mfma_f32_16x16x32_bf16(AL[0].b, Bh[0].b, acc, 0,0,0); \
            acc = __builtin_amdgcn_mfma_f32_16x16x32_bf16(AH[0].b, Bl[0].b, acc, 0,0,0); \
            acc = __builtin_amdgcn_mfma_f32_16x16x32_bf16(AH[1].b, Bh[1].b, acc, 0,0,0); \
            acc = __builtin_amdgcn_mfma_f32_16x16x32_bf16(AL[1].b, Bh[1].b, acc, 0,0,0); \
            acc = __builtin_amdgcn_mfma_f32_16x16x32_bf16(AH[1].b, Bl[1].b, acc, 0,0,0); \
            acc = __builtin_amdgcn_mfma_f32_16x16x32_bf16(AH[2].b, Bh[2].b, acc, 0,0,0); \
            acc = __builtin_amdgcn_mfma_f32_16x16x32_bf16(AL[2].b, Bh[2].b, acc, 0,0,0); \
            acc = __builtin_amdgcn_mfma_f32_16x16x32_bf16(AH[2].b, Bl[2].b, acc, 0,0,0); \
            const int p_ = lane & 15;                /* out col */                    \
            if (nt_ < 6) {                                                            \
                if (p_ < 8) {                                                         \
                    const int cp0_ = nt_ * 16 + (lane >> 4) * 4;                      \
                    const float4 b4_ = *reinterpret_cast<const float4*>(              \
                        (mat_ ? bq2 : bk2) + cp0_);                                   \
                    f32x4 av_;                                                        \
                    av_[0] = acc[0] + b4_.x; av_[1] = acc[1] + b4_.y;                 \
                    av_[2] = acc[2] + b4_.z; av_[3] = acc[3] + b4_.w;                 \
                    const int pr_ = p_ + 8 * mat_;                                    \
                    pack_hilo4(S, GKQH + pr_ * 200 + cp0_ * 2,                        \
                               GKQL + pr_ * 200 + cp0_ * 2, av_);                     \
                }                                                                     \
            } else if ((lane >> 4) == 0 && p_ < 8) {                                  \
                bias16[p_ + 8 * mat_] = acc[0];      /* row c'=96 = bias dot */       \
            }                                                                         \
        } while (0)

        frag_u B1h[3], B1l[3], B2h[3], B2l[3], B3h[3], B3l[3];
        LOADPAIR(B1h[0], B1l[0], mfrag, ((w + 4) * 3 + 0) * 2);
        LOADPAIR(B1h[1], B1l[1], mfrag, ((w + 4) * 3 + 1) * 2);
        LOADPAIR(B1h[2], B1l[2], mfrag, ((w + 4) * 3 + 2) * 2);
        G0TILE(w, B0h, B0l);
        LOADPAIR(B2h[0], B2l[0], mfrag, ((w + 8) * 3 + 0) * 2);
        LOADPAIR(B2h[1], B2l[1], mfrag, ((w + 8) * 3 + 1) * 2);
        LOADPAIR(B2h[2], B2l[2], mfrag, ((w + 8) * 3 + 2) * 2);
        G0TILE(w + 4, B1h, B1l);
        if (w < 2) {
            LOADPAIR(B3h[0], B3l[0], mfrag, ((w + 12) * 3 + 0) * 2);
            LOADPAIR(B3h[1], B3l[1], mfrag, ((w + 12) * 3 + 1) * 2);
            LOADPAIR(B3h[2], B3l[2], mfrag, ((w + 12) * 3 + 2) * 2);
        }
        G0TILE(w + 8, B2h, B2l);
        if (w < 2) G0TILE(w + 12, B3h, B3l);
        #undef G0TILE
    }
    bar();

    // ---- G1 (MFMA): logits; k rows -> Lraw, q-softmax in-register -> qat ----
    {
        frag_u Ah[3], Al[3];
        #pragma unroll
        for (int ks = 0; ks < 3; ++ks) {
            const int off = (lane & 15) * 200 + (ks * 32 + (lane >> 4) * 8) * 2;
            Ah[ks].s = *reinterpret_cast<const short8*>(S + GKQH + off);
            Al[ks].s = *reinterpret_cast<const short8*>(S + GKQL + off);
        }
        f32x4 acc = {0.f, 0.f, 0.f, 0.f};
        #pragma unroll
        for (int ks = 0; ks < 3; ++ks) {
            acc = __builtin_amdgcn_mfma_f32_16x16x32_bf16(Ah[ks].b, G1B[ks].b, acc, 0, 0, 0);
            acc = __builtin_amdgcn_mfma_f32_16x16x32_bf16(Al[ks].b, G1B[ks].b, acc, 0, 0, 0);
        }
        const int colL = w * 16 + (lane & 15);
        const int g = lane >> 4;
        if (g < 2) {
            #pragma unroll
            for (int rr = 0; rr < 4; ++rr) {
                const int pr = g * 4 + rr;
                Lraw[pr * 66 + colL] = acc[rr] + bias16[pr] + scal0;
            }
        } else {
            const bool isg3 = (g == 3);
            float v[4];
            #pragma unroll
            for (int rr = 0; rr < 4; ++rr)
                v[rr] = acc[rr] + bias16[8 + (g - 2) * 4 + rr] + scal1;
            float mymax = fmaxf(fmaxf(v[0], v[1]), isg3 ? v[2] : fmaxf(v[2], v[3]));
            const float omax = __shfl_xor(mymax, 16);
            const float mx = fmaxf(mymax, omax);
            float e[4];
            e[0] = __expf(v[0] - mx); e[1] = __expf(v[1] - mx); e[2] = __expf(v[2] - mx);
            e[3] = isg3 ? 0.f : __expf(v[3] - mx);
            float mysum = (e[0] + e[1]) + (e[2] + e[3]);
            const float osum = __shfl_xor(mysum, 16);
            const float inv = 1.f / (mysum + osum);
            float a[4], pa[4];
            #pragma unroll
            for (int rr = 0; rr < 4; ++rr) a[rr] = e[rr] * inv;
            #pragma unroll
            for (int rr = 0; rr < 4; ++rr) pa[rr] = __shfl_xor(a[rr], 16);
            if (!isg3) {
                frag_u qh, ql;
                #pragma unroll
                for (int p = 0; p < 4; ++p) {
                    const __bf16 hb = (__bf16)a[p];
                    qh.b[p] = hb; ql.b[p] = (__bf16)(a[p] - (float)hb);
                }
                #pragma unroll
                for (int p = 0; p < 4; ++p) {
                    const __bf16 hb = (__bf16)pa[p];     // pa[3] = 0 (partner e[3]=0)
                    qh.b[4 + p] = hb; ql.b[4 + p] = (__bf16)(pa[p] - (float)hb);
                }
                *reinterpret_cast<short8*>(S + QATH + colL * 16) = qh.s;
                *reinterpret_cast<short8*>(S + QATL + colL * 16) = ql.s;
            }
        }
    }
    bar();

    // ---- SM: k-softmax only (7 rows over 4 waves) -> attn frags ----
    {
        const int nrows = (w < 3) ? 2 : 1;
        #pragma unroll
        for (int rr = 0; rr < 2; ++rr) {
            if (rr < nrows) {
                const int pp = (w < 3) ? (w + 3 * rr) : 6;
                const float v = Lraw[pp * 66 + lane];
                float mx = v;
                #pragma unroll
                for (int off = 32; off; off >>= 1) mx = fmaxf(mx, __shfl_xor(mx, off));
                const float e = __expf(v - mx);
                float s = e;
                #pragma unroll
                for (int off = 32; off; off >>= 1) s += __shfl_xor(s, off);
                const float a = e / s;
                const __bf16 hb = (__bf16)a;
                const __bf16 lb = (__bf16)(a - (float)hb);
                const int ks = lane >> 5;
                const int off_b = ((pp + 16 * ((lane >> 3) & 3)) << 4) + ((lane & 7) << 1);
                *reinterpret_cast<__bf16*>(S + RB + (ks << 10) + off_b) = hb;
                *reinterpret_cast<__bf16*>(S + RB + ((2 + ks) << 10) + off_b) = lb;
            }
        }
    }
    bar();

    // ---- G2 (MFMA) + wvfrag prefetch: xv^T = xw(A) @ attn(B); packed b64 writes ----
    frag_u V0h[3], V0l[3], V1h[3], V1l[3];
    {
        LOADPAIR(V0h[0], V0l[0], wvfrag, (w * 3 + 0) * 2);
        LOADPAIR(V0h[1], V0l[1], wvfrag, (w * 3 + 1) * 2);
        LOADPAIR(V0h[2], V0l[2], wvfrag, (w * 3 + 2) * 2);
        if (w < 2) {
            LOADPAIR(V1h[0], V1l[0], wvfrag, ((4 + w) * 3 + 0) * 2);
            LOADPAIR(V1h[1], V1l[1], wvfrag, ((4 + w) * 3 + 1) * 2);
            LOADPAIR(V1h[2], V1l[2], wvfrag, ((4 + w) * 3 + 2) * 2);
        }

        frag_u Bh[2], Bl[2];
        #pragma unroll
        for (int ks = 0; ks < 2; ++ks) {
            Bh[ks].s = *reinterpret_cast<const short8*>(S + RB + (ks << 10) + (lane << 4));
            Bl[ks].s = *reinterpret_cast<const short8*>(S + RB + ((2 + ks) << 10) + (lane << 4));
        }
        const int mt0 = (w < 2) ? w * 2 : (w + 2);
        const int nmt = (w < 2) ? 2 : 1;
        for (int m = 0; m < nmt; ++m) {
            const int mt = mt0 + m;
            f32x4 acc = {0.f, 0.f, 0.f, 0.f};
            #pragma unroll
            for (int ks = 0; ks < 2; ++ks) {
                frag_u A;
                A.s = xws_fragA(S, mt, ks, lane);
                acc = __builtin_amdgcn_mfma_f32_16x16x32_bf16(A.b, Bh[ks].b, acc, 0, 0, 0);
                acc = __builtin_amdgcn_mfma_f32_16x16x32_bf16(A.b, Bl[ks].b, acc, 0, 0, 0);
            }
            const int p = lane & 15;
            if (p < 8) {                              // rows >=8 never read
                const int c0 = mt * 16 + (lane >> 4) * 4;
                pack_hilo4(S, XPH + p * 200 + c0 * 2, XPL + p * 200 + c0 * 2, acc);
            }
        }
    }
    bar();

    // ---- G3+P7 fused: av built in-register -> out (no av LDS, no final barrier) ----
    {
        const bool row7 = ((lane & 15) & 7) == 7;    // xv row 7 = garbage guard
        frag_u Ah[3], Al[3];                         // A-frag of xv: lane = p + 16kblk
        #pragma unroll
        for (int ks = 0; ks < 3; ++ks) {
            const int off = ((lane & 15) & 7) * 200 + (ks * 32 + (lane >> 4) * 8) * 2;
            Ah[ks].s = row7 ? zero8 : *reinterpret_cast<const short8*>(S + XPH + off);
            Al[ks].s = row7 ? zero8 : *reinterpret_cast<const short8*>(S + XPL + off);
        }

        frag_u PA0h, PA0l, PA1h, PA1l;               // P7 A-frags (av[o][p0..7])
        #define G3ACC(OT, VH, VL, DSTH, DSTL) do {                                    \
            f32x4 acc = {0.f, 0.f, 0.f, 0.f};                                         \
            acc = __builtin_amdgcn_mfma_f32_16x16x32_bf16(Ah[0].b, VH[0].b, acc, 0,0,0); \
            acc = __builtin_amdgcn_mfma_f32_16x16x32_bf16(Al[0].b, VH[0].b, acc, 0,0,0); \
            acc = __builtin_amdgcn_mfma_f32_16x16x32_bf16(Ah[0].b, VL[0].b, acc, 0,0,0); \
            acc = __builtin_amdgcn_mfma_f32_16x16x32_bf16(Ah[1].b, VH[1].b, acc, 0,0,0); \
            acc = __builtin_amdgcn_mfma_f32_16x16x32_bf16(Al[1].b, VH[1].b, acc, 0,0,0); \
            acc = __builtin_amdgcn_mfma_f32_16x16x32_bf16(Ah[1].b, VL[1].b, acc, 0,0,0); \
            acc = __builtin_amdgcn_mfma_f32_16x16x32_bf16(Ah[2].b, VH[2].b, acc, 0,0,0); \
            acc = __builtin_amdgcn_mfma_f32_16x16x32_bf16(Al[2].b, VH[2].b, acc, 0,0,0); \
            acc = __builtin_amdgcn_mfma_f32_16x16x32_bf16(Ah[2].b, VL[2].b, acc, 0,0,0); \
            float p47[4];                                                             \
            _Pragma("unroll")                                                         \
            for (int rr = 0; rr < 4; ++rr) p47[rr] = __shfl_xor(acc[rr], 16);         \
            if ((lane >> 4) == 0) {                                                   \
                const float bvo_ = bv[(OT) * 16 + (lane & 15)];                       \
                float vv[8] = {acc[0] + bvo_, acc[1] + bvo_, acc[2] + bvo_,           \
                               acc[3] + bvo_, p47[0] + bvo_, p47[1] + bvo_,           \
                               p47[2] + bvo_, p47[3] + bvo_};                         \
                _Pragma("unroll")                                                     \
                for (int j = 0; j < 8; ++j) {                                         \
                    const __bf16 hb = (__bf16)vv[j];                                  \
                    (DSTH).b[j] = hb;                                                 \
                    (DSTL).b[j] = (__bf16)(vv[j] - (float)hb);                        \
                }                                                                     \
            } else { (DSTH).s = zero8; (DSTL).s = zero8; }                            \
        } while (0)
        G3ACC(w, V0h, V0l, PA0h, PA0l);
        if (w < 2) G3ACC(4 + w, V1h, V1l, PA1h, PA1l);
        #undef G3ACC

        // P7: out^T[o][l] = av(A, in-reg) @ qat^T(B); each wave: own o-tiles, all l
        #pragma unroll
        for (int lt = 0; lt < 4; ++lt) {
            const int ll = lt * 16 + (lane & 15);
            frag_u Bh, Bl;
            if ((lane >> 4) == 0) {
                Bh.s = *reinterpret_cast<const short8*>(S + QATH + ll * 16);
                Bl.s = *reinterpret_cast<const short8*>(S + QATL + ll * 16);
            } else { Bh.s = zero8; Bl.s = zero8; }
            const int obase = b * C_ * HWp + (h0 + (ll >> 3)) * Wimg + w0 + (ll & 7);
            {
                f32x4 a0 = {0.f, 0.f, 0.f, 0.f};
                a0 = __builtin_amdgcn_mfma_f32_16x16x32_bf16(PA0h.b, Bh.b, a0, 0, 0, 0);
                a0 = __builtin_amdgcn_mfma_f32_16x16x32_bf16(PA0h.b, Bl.b, a0, 0, 0, 0);
                a0 = __builtin_amdgcn_mfma_f32_16x16x32_bf16(PA0l.b, Bh.b, a0, 0, 0, 0);
                #pragma unroll
                for (int rr = 0; rr < 4; ++rr) {
                    const int o = w * 16 + (lane >> 4) * 4 + rr;
                    out[obase + o * HWp] = a0[rr];
                }
            }
            if (w < 2) {
                f32x4 a1 = {0.f, 0.f, 0.f, 0.f};
                a1 = __builtin_amdgcn_mfma_f32_16x16x32_bf16(PA1h.b, Bh.b, a1, 0, 0, 0);
                a1 = __builtin_amdgcn_mfma_f32_16x16x32_bf16(PA1h.b, Bl.b, a1, 0, 0, 0);
                a1 = __builtin_amdgcn_mfma_f32_16x16x32_bf16(PA1l.b, Bh.b, a1, 0, 0, 0);
                #pragma unroll
                for (int rr = 0; rr < 4; ++rr) {
                    const int o = (4 + w) * 16 + (lane >> 4) * 4 + rr;
                    out[obase + o * HWp] = a1[rr];
                }
            }
        }
    }
}

// ---------------- launch ----------------

extern "C" void kernel_launch(void* const* d_in, const int* in_sizes, int n_in,
                              void* d_out, int out_size, void* d_ws, size_t ws_size,
                              hipStream_t stream)
{
    const float* x  = (const float*)d_in[0];
    const float* Wv = (const float*)d_in[1];
    const float* bv = (const float*)d_in[2];
    const float* Wq = (const float*)d_in[3];
    const float* bq = (const float*)d_in[4];
    const float* Wk = (const float*)d_in[5];
    const float* bk = (const float*)d_in[6];
    float* out = (float*)d_out;

    float* ws = (float*)d_ws;
    float* Mk   = ws;                 // 9216
    float* Mq   = ws + 9216;
    float* uk   = ws + 18432;
    float* uq   = ws + 18528;
    float* bk2  = ws + 18624;
    float* bq2  = ws + 18720;
    float* scal = ws + 18816;
    unsigned char* wsb = (unsigned char*)d_ws;

    hipLaunchKernelGGL(precompute_mv, dim3(97), dim3(C_), 0, stream,
                       Wq, Wk, bq, bk, Mk, Mq, uk, uq, bk2, bq2, scal);
    hipLaunchKernelGGL(precompute_frags, dim3(120), dim3(64), 0, stream,
                       ws, Wv, wsb);
    hipLaunchKernelGGL(camixer_main, dim3(8 * NWIN * NWIN), dim3(256), 0, stream,
                       x, bv, bk2, bq2, scal,
                       wsb + WS_FRAG_BYTE, wsb + WS_WV_BYTE, out);
}

// Round 21
// 71.779 us; speedup vs baseline: 2.5825x; 1.9753x over previous
//
#include <hip/hip_runtime.h>

// CAMixer agent-attention, fused per-window (8x8).  v21 = v18 restored verbatim
// (best passing: 71.8us). v19/v20's G1-gather hoist caused scratch spills across
// the barrier in both launch-bound configs -> reverted.
//
// Algebra (exact refactor, verified round 1):
//   agent   = conv(pool(x), Wq)
//   k-logit[p][l] = xw[l]·gk[p] + bkd[p],  gk = xp @ Mk + bk2,  Mk = Wq^T Wk
//   q-logit[l][p] = xw[l]·gq[p] + bqd[p],  gq = xp @ Mq + bq2,  Mq = Wq^T Wq
//   agent_v = (a_attn @ xw) @ Wv^T + bv
//
// MFMA conventions (verified v5-v18):
//   A-frag: lane = row + 16*kblk holds A[row][ks*32 + kblk*8 + j], j=0..7
//   B-frag: lane = col + 16*kblk holds B[ks*32 + kblk*8 + j][col]
//   C-frag: col = lane&15, row = (lane>>4)*4 + reg
//
// XWS layout (v7-proven): element (c,l) at byte c*128 + ((l*2) ^ ((c&7)<<4))

constexpr int C_   = 96;
constexpr int Wimg = 192;
constexpr int HWp  = 192 * 192;
constexpr int NWIN = 24;
constexpr int Pp   = 7;

typedef __attribute__((ext_vector_type(8))) __bf16 bf16x8;
typedef __attribute__((ext_vector_type(4))) __bf16 bf16x4;
typedef __attribute__((ext_vector_type(8))) short  short8;
typedef __attribute__((ext_vector_type(4))) float  f32x4;
union frag_u { short8 s; bf16x8 b; };

// ---- LDS byte offsets (total 25,024 B) ----
constexpr int XWS   = 0;        // xw bf16 [96][64], 128B rows, XOR-swizzled (12,288)
constexpr int RA    = 12288;    // 4,224: xp hi/lo [8][100] -> Lraw[8][66]f32 -> xv hi/lo
constexpr int XPH   = RA;
constexpr int XPL   = RA + 1600;
constexpr int LRAW  = RA;
constexpr int RB    = 16512;    // 6,400: gkq hi/lo [16][100] -> attn(4x1KB)
constexpr int GKQH  = RB;
constexpr int GKQL  = RB + 3200;
constexpr int QATH  = 22912;    // qat hi [64][16B]
constexpr int QATL  = 23936;    // qat lo [64][16B]
constexpr int BIAS  = 24960;    // f32[16]
constexpr int SMEMB = 25024;

// ---- ws offsets ----
// float idx: Mk 0, Mq 9216, uk 18432, uq 18528, bk2 18624, bq2 18720, scal 18816
constexpr int WS_FRAG_BYTE = 18944 * 4;                 // Mext frags: 84 slots x 1KB
constexpr int WS_WV_BYTE   = WS_FRAG_BYTE + 84 * 1024;  // Wv frags: 36 slots x 1KB

// ---------------- helpers ----------------

__device__ __forceinline__ void bar() {
    asm volatile("s_waitcnt lgkmcnt(0)" ::: "memory");
    __builtin_amdgcn_s_barrier();
}

__device__ __forceinline__ short8 xws_fragA(const unsigned char* S, int mt, int ks, int lane) {
    const int c  = mt * 16 + (lane & 15);
    const int l2 = ks * 64 + ((lane >> 4) << 4);
    return *reinterpret_cast<const short8*>(S + XWS + c * 128 + (l2 ^ ((c & 7) << 4)));
}

// pack a C-frag (4 consecutive columns) into one b64 hi + one b64 lo write
__device__ __forceinline__ void pack_hilo4(unsigned char* S, int hi_off, int lo_off,
                                           const f32x4 acc) {
    bf16x4 h, l;
    #pragma unroll
    for (int i = 0; i < 4; ++i) {
        h[i] = (__bf16)acc[i];
        l[i] = (__bf16)(acc[i] - (float)h[i]);
    }
    *reinterpret_cast<bf16x4*>(S + hi_off) = h;
    *reinterpret_cast<bf16x4*>(S + lo_off) = l;
}

// ---------------- precompute (weights only; mats+vecs merged, v11 patterns) ----------------

__global__ void precompute_mv(const float* __restrict__ Wq,
                              const float* __restrict__ Wk,
                              const float* __restrict__ bq,
                              const float* __restrict__ bk,
                              float* __restrict__ Mk,  float* __restrict__ Mq,
                              float* __restrict__ uk,  float* __restrict__ uq,
                              float* __restrict__ bk2, float* __restrict__ bq2,
                              float* __restrict__ scal)
{
    const int bid = blockIdx.x;
    if (bid < 96) {
        const int c  = bid;
        const int cp = threadIdx.x;
        float ak = 0.f, aq = 0.f;
        for (int a = 0; a < C_; ++a) {
            const float wq = Wq[a * C_ + c];
            ak = fmaf(wq, Wk[a * C_ + cp], ak);
            aq = fmaf(wq, Wq[a * C_ + cp], aq);
        }
        Mk[c * C_ + cp] = ak;
        Mq[c * C_ + cp] = aq;
    } else {
        const int c = threadIdx.x;
        float a_uk = 0.f, a_uq = 0.f, a_bk2 = 0.f, a_bq2 = 0.f;
        for (int a = 0; a < C_; ++a) {
            const float wqc = Wq[a * C_ + c];
            a_uk  = fmaf(wqc, bk[a], a_uk);
            a_uq  = fmaf(wqc, bq[a], a_uq);
            a_bk2 = fmaf(bq[a], Wk[a * C_ + c], a_bk2);
            a_bq2 = fmaf(bq[a], Wq[a * C_ + c], a_bq2);
        }
        uk[c] = a_uk; uq[c] = a_uq; bk2[c] = a_bk2; bq2[c] = a_bq2;
        if (c == 0) {
            float sk = 0.f, sq = 0.f;
            for (int a = 0; a < C_; ++a) { sk += bq[a] * bk[a]; sq += bq[a] * bq[a]; }
            scal[0] = sk; scal[1] = sq;
        }
    }
}

// frag tables: bid<84: Mext B-frags slot=((mat*7+nt)*3+ks)*2+hl; else Wv A-frags.
__global__ void precompute_frags(const float* __restrict__ ws,
                                 const float* __restrict__ Wv,
                                 unsigned char* __restrict__ wsb)
{
    const int bid = blockIdx.x, lane = threadIdx.x;
    short8 o;
    if (bid < 84) {
        const int hl = bid & 1, ks = (bid >> 1) % 3, nt = (bid / 6) % 7, mat = bid / 42;
        const float* M = ws + (mat ? 9216 : 0);
        const float* u = ws + (mat ? 18528 : 18432);
        const int col = nt * 16 + (lane & 15);
        #pragma unroll
        for (int j = 0; j < 8; ++j) {
            const int k = ks * 32 + (lane >> 4) * 8 + j;
            const float raw = (col < 96) ? M[k * 96 + col] : ((col == 96) ? u[k] : 0.f);
            const __bf16 hi = (__bf16)raw;
            union { __bf16 h; short s; } cv;
            cv.h = hl ? (__bf16)(raw - (float)hi) : hi;
            o[j] = cv.s;
        }
        *reinterpret_cast<short8*>(wsb + WS_FRAG_BYTE + bid * 1024 + lane * 16) = o;
    } else {
        const int wb = bid - 84;
        const int hl = wb & 1, ks = (wb >> 1) % 3, mt = wb / 6;
        const int row = mt * 16 + (lane & 15);
        #pragma unroll
        for (int j = 0; j < 8; ++j) {
            const int c = ks * 32 + (lane >> 4) * 8 + j;
            const float raw = Wv[row * 96 + c];
            const __bf16 hi = (__bf16)raw;
            union { __bf16 h; short s; } cv;
            cv.h = hl ? (__bf16)(raw - (float)hi) : hi;
            o[j] = cv.s;
        }
        *reinterpret_cast<short8*>(wsb + WS_WV_BYTE + wb * 1024 + lane * 16) = o;
    }
}

#define LOADPAIR(dstH, dstL, tab, slot_h) do {                                               \
    (dstH).s = *reinterpret_cast<const short8*>((tab) + (slot_h) * 1024 + (lane << 4));      \
    (dstL).s = *reinterpret_cast<const short8*>((tab) + ((slot_h) + 1) * 1024 + (lane << 4));\
} while (0)

// ---------------- main fused kernel ----------------

__global__ __launch_bounds__(256, 5) void camixer_main(
    const float* __restrict__ x,
    const float* __restrict__ bv,
    const float* __restrict__ bk2,
    const float* __restrict__ bq2,
    const float* __restrict__ scal,
    const unsigned char* __restrict__ mfrag,
    const unsigned char* __restrict__ wvfrag,
    float* __restrict__ out)
{
    __shared__ __align__(16) unsigned char S[SMEMB];
    float* Lraw   = (float*)(S + LRAW);  // [8][66] (k rows only)
    float* bias16 = (float*)(S + BIAS);  // [16]

    const int t = threadIdx.x;
    const int lane = t & 63, w = t >> 6;
    const int wid = ((blockIdx.x & 7) * 576) + (blockIdx.x >> 3);  // bijective XCD swizzle
    const int b  = wid / (NWIN * NWIN);
    const int r  = wid % (NWIN * NWIN);
    const int h0 = (r / NWIN) * 8;
    const int w0 = (r % NWIN) * 8;
    const int base = b * C_ * HWp + h0 * Wimg + w0;
    const float scal0 = scal[0], scal1 = scal[1];
    const short8 zero8 = {0, 0, 0, 0, 0, 0, 0, 0};

    // ---- prefetch G0 tile tt=w (A-operand Mext^T frags): under P0 + G_P ----
    frag_u B0h[3], B0l[3];
    LOADPAIR(B0h[0], B0l[0], mfrag, (w * 3 + 0) * 2);
    LOADPAIR(B0h[1], B0l[1], mfrag, (w * 3 + 1) * 2);
    LOADPAIR(B0h[2], B0l[2], mfrag, (w * 3 + 2) * 2);

    // ---- P0: x window -> bf16 XOR-swizzled row-major (single copy) ----
    {
        const float4* x4 = reinterpret_cast<const float4*>(x);
        #pragma unroll
        for (int rr = 0; rr < 2; ++rr) {
            const int idx = t + (rr << 8);          // 384 = 24 c4 x 8 dh x 2 dw4
            if (idx < 384) {
                const int dw4 = idx & 1;
                const int dh  = (idx >> 1) & 7;
                const int c4  = idx >> 4;
                const int c0 = c4 * 4, l0 = dh * 8 + dw4 * 4;
                #pragma unroll
                for (int j = 0; j < 4; ++j) {
                    const int c = c0 + j;
                    const float4 v = x4[(base + c * HWp + dh * Wimg + dw4 * 4) >> 2];
                    bf16x4 d = {(__bf16)v.x, (__bf16)v.y, (__bf16)v.z, (__bf16)v.w};
                    *reinterpret_cast<bf16x4*>(S + XWS + c * 128 + ((l0 * 2) ^ ((c & 7) << 4))) = d;
                }
            }
        }
    }
    bar();

    // ---- G_P (MFMA, swapped): xp^T-tiles = xw(A) @ P(B); out[c][p], packed b64 writes ----
    {
        frag_u PBh[2], PBl[2];                       // B-frag of P: lane = p + 16*kblk
        {
            const int p = lane & 15;
            const __bf16 PH = (__bf16)0.1f;
            const __bf16 PL = (__bf16)(0.1f - (float)PH);
            const int sp = (p < 7) ? ((p << 6) / 7) : 1000;
            #pragma unroll
            for (int ks = 0; ks < 2; ++ks)
                #pragma unroll
                for (int j = 0; j < 8; ++j) {
                    const int l = ks * 32 + (lane >> 4) * 8 + j;
                    const bool in = (l >= sp) && (l < sp + 10);
                    PBh[ks].b[j] = in ? PH : (__bf16)0.f;
                    PBl[ks].b[j] = in ? PL : (__bf16)0.f;
                }
        }
        #pragma unroll
        for (int rnd = 0; rnd < 2; ++rnd) {
            const int mt = rnd ? (4 + w) : w;        // c-tile
            if (rnd == 0 || w < 2) {
                f32x4 acc = {0.f, 0.f, 0.f, 0.f};
                #pragma unroll
                for (int ks = 0; ks < 2; ++ks) {
                    frag_u A;
                    A.s = xws_fragA(S, mt, ks, lane);
                    acc = __builtin_amdgcn_mfma_f32_16x16x32_bf16(A.b, PBh[ks].b, acc, 0, 0, 0);
                    acc = __builtin_amdgcn_mfma_f32_16x16x32_bf16(A.b, PBl[ks].b, acc, 0, 0, 0);
                }
                const int p = lane & 15;             // out col
                if (p < 8) {
                    const int c0 = mt * 16 + (lane >> 4) * 4;
                    pack_hilo4(S, XPH + p * 200 + c0 * 2, XPL + p * 200 + c0 * 2, acc);
                }
            }
        }
    }
    bar();

    // ---- G0 (MFMA, swapped+pipelined): gkq^T-tiles = Mext^T(A) @ xp^T(B) ----
    {
        frag_u Bh[3], Bl[3];                         // B-frag of xp^T == A-frag of xp
        #pragma unroll
        for (int ks = 0; ks < 3; ++ks) {
            const int off = ((lane & 15) & 7) * 200 + (ks * 32 + (lane >> 4) * 8) * 2;
            Bh[ks].s = *reinterpret_cast<const short8*>(S + XPH + off);
            Bl[ks].s = *reinterpret_cast<const short8*>(S + XPL + off);
        }

        #define G0TILE(TT, AH, AL) do {                                               \
            const int tt_ = (TT);                                                     \
            const int mat_ = (tt_ >= 7) ? 1 : 0;                                      \
            const int nt_  = tt_ - 7 * mat_;         /* c'-tile */                    \
            f32x4 acc = {0.f, 0.f, 0.f, 0.f};                                         \
            acc = __builtin_amdgcn_mfma_f32_16x16x32_bf16(AH[0].b, Bh[0].b, acc, 0,0,0); \
            acc = __builtin_amdgcn_mfma_f32_16x16x32_bf16(AL[0].b, Bh[0].b, acc, 0,0,0); \
            acc = __builtin_amdgcn_mfma_f32_16x16x32_bf16(AH[0].b, Bl[0].b, acc, 0,0,0); \
            acc = __builtin_amdgcn_mfma_f32_16x16x32_bf16(AH[1].b, Bh[1].b, acc, 0,0,0); \
            acc = __builtin_amdgcn_mfma_f32_16x16x32_bf16(AL[1].b, Bh[1].b, acc, 0,0,0); \
            acc = __builtin_amdgcn_mfma_f32_16x16x32_bf16(AH[1].b, Bl[1].b, acc, 0,0,0); \
            acc = __builtin_amdgcn_mfma_f32_16x16x32_bf16(AH[2].b, Bh[2].b, acc, 0,0,0); \
            acc = __builtin_amdgcn_mfma_f32_16x16x32_bf16(AL[2].b, Bh[2].b, acc, 0,0,0); \
            acc = __builtin_amdgcn_mfma_f32_16x16x32_bf16(AH[2].b, Bl[2].b, acc, 0,0,0); \
            const int p_ = lane & 15;                /* out col */                    \
            if (nt_ < 6) {                                                            \
                if (p_ < 8) {                                                         \
                    const int cp0_ = nt_ * 16 + (lane >> 4) * 4;                      \
                    const float4 b4_ = *reinterpret_cast<const float4*>(              \
                        (mat_ ? bq2 : bk2) + cp0_);                                   \
                    f32x4 av_;                                                        \
                    av_[0] = acc[0] + b4_.x; av_[1] = acc[1] + b4_.y;                 \
                    av_[2] = acc[2] + b4_.z; av_[3] = acc[3] + b4_.w;                 \
                    const int pr_ = p_ + 8 * mat_;                                    \
                    pack_hilo4(S, GKQH + pr_ * 200 + cp0_ * 2,                        \
                               GKQL + pr_ * 200 + cp0_ * 2, av_);                     \
                }                                                                     \
            } else if ((lane >> 4) == 0 && p_ < 8) {                                  \
                bias16[p_ + 8 * mat_] = acc[0];      /* row c'=96 = bias dot */       \
            }                                                                         \
        } while (0)

        frag_u B1h[3], B1l[3], B2h[3], B2l[3], B3h[3], B3l[3];
        LOADPAIR(B1h[0], B1l[0], mfrag, ((w + 4) * 3 + 0) * 2);
        LOADPAIR(B1h[1], B1l[1], mfrag, ((w + 4) * 3 + 1) * 2);
        LOADPAIR(B1h[2], B1l[2], mfrag, ((w + 4) * 3 + 2) * 2);
        G0TILE(w, B0h, B0l);
        LOADPAIR(B2h[0], B2l[0], mfrag, ((w + 8) * 3 + 0) * 2);
        LOADPAIR(B2h[1], B2l[1], mfrag, ((w + 8) * 3 + 1) * 2);
        LOADPAIR(B2h[2], B2l[2], mfrag, ((w + 8) * 3 + 2) * 2);
        G0TILE(w + 4, B1h, B1l);
        if (w < 2) {
            LOADPAIR(B3h[0], B3l[0], mfrag, ((w + 12) * 3 + 0) * 2);
            LOADPAIR(B3h[1], B3l[1], mfrag, ((w + 12) * 3 + 1) * 2);
            LOADPAIR(B3h[2], B3l[2], mfrag, ((w + 12) * 3 + 2) * 2);
        }
        G0TILE(w + 8, B2h, B2l);
        if (w < 2) G0TILE(w + 12, B3h, B3l);
        #undef G0TILE
    }
    bar();

    // ---- G1 (MFMA): logits; k rows -> Lraw, q-softmax in-register -> qat ----
    {
        frag_u B[3];
        {
            const int l2 = (w * 16 + (lane & 15)) * 2;
            const int kb = (lane >> 4) << 10;
            #pragma unroll
            for (int j = 0; j < 8; ++j) {
                const int aj = kb + j * 128 + (l2 ^ (j << 4));
                B[0].b[j] = *reinterpret_cast<const __bf16*>(S + XWS + aj);
                B[1].b[j] = *reinterpret_cast<const __bf16*>(S + XWS + 4096 + aj);
                B[2].b[j] = *reinterpret_cast<const __bf16*>(S + XWS + 8192 + aj);
            }
        }
        frag_u Ah[3], Al[3];
        #pragma unroll
        for (int ks = 0; ks < 3; ++ks) {
            const int off = (lane & 15) * 200 + (ks * 32 + (lane >> 4) * 8) * 2;
            Ah[ks].s = *reinterpret_cast<const short8*>(S + GKQH + off);
            Al[ks].s = *reinterpret_cast<const short8*>(S + GKQL + off);
        }
        f32x4 acc = {0.f, 0.f, 0.f, 0.f};
        #pragma unroll
        for (int ks = 0; ks < 3; ++ks) {
            acc = __builtin_amdgcn_mfma_f32_16x16x32_bf16(Ah[ks].b, B[ks].b, acc, 0, 0, 0);
            acc = __builtin_amdgcn_mfma_f32_16x16x32_bf16(Al[ks].b, B[ks].b, acc, 0, 0, 0);
        }
        const int colL = w * 16 + (lane & 15);
        const int g = lane >> 4;
        if (g < 2) {
            #pragma unroll
            for (int rr = 0; rr < 4; ++rr) {
                const int pr = g * 4 + rr;
                Lraw[pr * 66 + colL] = acc[rr] + bias16[pr] + scal0;
            }
        } else {
            const bool isg3 = (g == 3);
            float v[4];
            #pragma unroll
            for (int rr = 0; rr < 4; ++rr)
                v[rr] = acc[rr] + bias16[8 + (g - 2) * 4 + rr] + scal1;
            float mymax = fmaxf(fmaxf(v[0], v[1]), isg3 ? v[2] : fmaxf(v[2], v[3]));
            const float omax = __shfl_xor(mymax, 16);
            const float mx = fmaxf(mymax, omax);
            float e[4];
            e[0] = __expf(v[0] - mx); e[1] = __expf(v[1] - mx); e[2] = __expf(v[2] - mx);
            e[3] = isg3 ? 0.f : __expf(v[3] - mx);
            float mysum = (e[0] + e[1]) + (e[2] + e[3]);
            const float osum = __shfl_xor(mysum, 16);
            const float inv = 1.f / (mysum + osum);
            float a[4], pa[4];
            #pragma unroll
            for (int rr = 0; rr < 4; ++rr) a[rr] = e[rr] * inv;
            #pragma unroll
            for (int rr = 0; rr < 4; ++rr) pa[rr] = __shfl_xor(a[rr], 16);
            if (!isg3) {
                frag_u qh, ql;
                #pragma unroll
                for (int p = 0; p < 4; ++p) {
                    const __bf16 hb = (__bf16)a[p];
                    qh.b[p] = hb; ql.b[p] = (__bf16)(a[p] - (float)hb);
                }
                #pragma unroll
                for (int p = 0; p < 4; ++p) {
                    const __bf16 hb = (__bf16)pa[p];     // pa[3] = 0 (partner e[3]=0)
                    qh.b[4 + p] = hb; ql.b[4 + p] = (__bf16)(pa[p] - (float)hb);
                }
                *reinterpret_cast<short8*>(S + QATH + colL * 16) = qh.s;
                *reinterpret_cast<short8*>(S + QATL + colL * 16) = ql.s;
            }
        }
    }
    bar();

    // ---- SM: k-softmax only (7 rows over 4 waves) -> attn frags ----
    {
        const int nrows = (w < 3) ? 2 : 1;
        #pragma unroll
        for (int rr = 0; rr < 2; ++rr) {
            if (rr < nrows) {
                const int pp = (w < 3) ? (w + 3 * rr) : 6;
                const float v = Lraw[pp * 66 + lane];
                float mx = v;
                #pragma unroll
                for (int off = 32; off; off >>= 1) mx = fmaxf(mx, __shfl_xor(mx, off));
                const float e = __expf(v - mx);
                float s = e;
                #pragma unroll
                for (int off = 32; off; off >>= 1) s += __shfl_xor(s, off);
                const float a = e / s;
                const __bf16 hb = (__bf16)a;
                const __bf16 lb = (__bf16)(a - (float)hb);
                const int ks = lane >> 5;
                const int off_b = ((pp + 16 * ((lane >> 3) & 3)) << 4) + ((lane & 7) << 1);
                *reinterpret_cast<__bf16*>(S + RB + (ks << 10) + off_b) = hb;
                *reinterpret_cast<__bf16*>(S + RB + ((2 + ks) << 10) + off_b) = lb;
            }
        }
    }
    bar();

    // ---- G2 (MFMA) + wvfrag prefetch: xv^T = xw(A) @ attn(B); packed b64 writes ----
    frag_u V0h[3], V0l[3], V1h[3], V1l[3];
    {
        LOADPAIR(V0h[0], V0l[0], wvfrag, (w * 3 + 0) * 2);
        LOADPAIR(V0h[1], V0l[1], wvfrag, (w * 3 + 1) * 2);
        LOADPAIR(V0h[2], V0l[2], wvfrag, (w * 3 + 2) * 2);
        if (w < 2) {
            LOADPAIR(V1h[0], V1l[0], wvfrag, ((4 + w) * 3 + 0) * 2);
            LOADPAIR(V1h[1], V1l[1], wvfrag, ((4 + w) * 3 + 1) * 2);
            LOADPAIR(V1h[2], V1l[2], wvfrag, ((4 + w) * 3 + 2) * 2);
        }

        frag_u Bh[2], Bl[2];
        #pragma unroll
        for (int ks = 0; ks < 2; ++ks) {
            Bh[ks].s = *reinterpret_cast<const short8*>(S + RB + (ks << 10) + (lane << 4));
            Bl[ks].s = *reinterpret_cast<const short8*>(S + RB + ((2 + ks) << 10) + (lane << 4));
        }
        const int mt0 = (w < 2) ? w * 2 : (w + 2);
        const int nmt = (w < 2) ? 2 : 1;
        for (int m = 0; m < nmt; ++m) {
            const int mt = mt0 + m;
            f32x4 acc = {0.f, 0.f, 0.f, 0.f};
            #pragma unroll
            for (int ks = 0; ks < 2; ++ks) {
                frag_u A;
                A.s = xws_fragA(S, mt, ks, lane);
                acc = __builtin_amdgcn_mfma_f32_16x16x32_bf16(A.b, Bh[ks].b, acc, 0, 0, 0);
                acc = __builtin_amdgcn_mfma_f32_16x16x32_bf16(A.b, Bl[ks].b, acc, 0, 0, 0);
            }
            const int p = lane & 15;
            if (p < 8) {                              // rows >=8 never read
                const int c0 = mt * 16 + (lane >> 4) * 4;
                pack_hilo4(S, XPH + p * 200 + c0 * 2, XPL + p * 200 + c0 * 2, acc);
            }
        }
    }
    bar();

    // ---- G3+P7 fused: av built in-register -> out (no av LDS, no final barrier) ----
    {
        const bool row7 = ((lane & 15) & 7) == 7;    // xv row 7 = garbage guard
        frag_u Ah[3], Al[3];                         // A-frag of xv: lane = p + 16kblk
        #pragma unroll
        for (int ks = 0; ks < 3; ++ks) {
            const int off = ((lane & 15) & 7) * 200 + (ks * 32 + (lane >> 4) * 8) * 2;
            Ah[ks].s = row7 ? zero8 : *reinterpret_cast<const short8*>(S + XPH + off);
            Al[ks].s = row7 ? zero8 : *reinterpret_cast<const short8*>(S + XPL + off);
        }

        frag_u PA0h, PA0l, PA1h, PA1l;               // P7 A-frags (av[o][p0..7])
        #define G3ACC(OT, VH, VL, DSTH, DSTL) do {                                    \
            f32x4 acc = {0.f, 0.f, 0.f, 0.f};                                         \
            acc = __builtin_amdgcn_mfma_f32_16x16x32_bf16(Ah[0].b, VH[0].b, acc, 0,0,0); \
            acc = __builtin_amdgcn_mfma_f32_16x16x32_bf16(Al[0].b, VH[0].b, acc, 0,0,0); \
            acc = __builtin_amdgcn_mfma_f32_16x16x32_bf16(Ah[0].b, VL[0].b, acc, 0,0,0); \
            acc = __builtin_amdgcn_mfma_f32_16x16x32_bf16(Ah[1].b, VH[1].b, acc, 0,0,0); \
            acc = __builtin_amdgcn_mfma_f32_16x16x32_bf16(Al[1].b, VH[1].b, acc, 0,0,0); \
            acc = __builtin_amdgcn_mfma_f32_16x16x32_bf16(Ah[1].b, VL[1].b, acc, 0,0,0); \
            acc = __builtin_amdgcn_mfma_f32_16x16x32_bf16(Ah[2].b, VH[2].b, acc, 0,0,0); \
            acc = __builtin_amdgcn_mfma_f32_16x16x32_bf16(Al[2].b, VH[2].b, acc, 0,0,0); \
            acc = __builtin_amdgcn_mfma_f32_16x16x32_bf16(Ah[2].b, VL[2].b, acc, 0,0,0); \
            float p47[4];                                                             \
            _Pragma("unroll")                                                         \
            for (int rr = 0; rr < 4; ++rr) p47[rr] = __shfl_xor(acc[rr], 16);         \
            if ((lane >> 4) == 0) {                                                   \
                const float bvo_ = bv[(OT) * 16 + (lane & 15)];                       \
                float vv[8] = {acc[0] + bvo_, acc[1] + bvo_, acc[2] + bvo_,           \
                               acc[3] + bvo_, p47[0] + bvo_, p47[1] + bvo_,           \
                               p47[2] + bvo_, p47[3] + bvo_};                         \
                _Pragma("unroll")                                                     \
                for (int j = 0; j < 8; ++j) {                                         \
                    const __bf16 hb = (__bf16)vv[j];                                  \
                    (DSTH).b[j] = hb;                                                 \
                    (DSTL).b[j] = (__bf16)(vv[j] - (float)hb);                        \
                }                                                                     \
            } else { (DSTH).s = zero8; (DSTL).s = zero8; }                            \
        } while (0)
        G3ACC(w, V0h, V0l, PA0h, PA0l);
        if (w < 2) G3ACC(4 + w, V1h, V1l, PA1h, PA1l);
        #undef G3ACC

        // P7: out^T[o][l] = av(A, in-reg) @ qat^T(B); each wave: own o-tiles, all l
        #pragma unroll
        for (int lt = 0; lt < 4; ++lt) {
            const int ll = lt * 16 + (lane & 15);
            frag_u Bh, Bl;
            if ((lane >> 4) == 0) {
                Bh.s = *reinterpret_cast<const short8*>(S + QATH + ll * 16);
                Bl.s = *reinterpret_cast<const short8*>(S + QATL + ll * 16);
            } else { Bh.s = zero8; Bl.s = zero8; }
            const int obase = b * C_ * HWp + (h0 + (ll >> 3)) * Wimg + w0 + (ll & 7);
            {
                f32x4 a0 = {0.f, 0.f, 0.f, 0.f};
                a0 = __builtin_amdgcn_mfma_f32_16x16x32_bf16(PA0h.b, Bh.b, a0, 0, 0, 0);
                a0 = __builtin_amdgcn_mfma_f32_16x16x32_bf16(PA0h.b, Bl.b, a0, 0, 0, 0);
                a0 = __builtin_amdgcn_mfma_f32_16x16x32_bf16(PA0l.b, Bh.b, a0, 0, 0, 0);
                #pragma unroll
                for (int rr = 0; rr < 4; ++rr) {
                    const int o = w * 16 + (lane >> 4) * 4 + rr;
                    out[obase + o * HWp] = a0[rr];
                }
            }
            if (w < 2) {
                f32x4 a1 = {0.f, 0.f, 0.f, 0.f};
                a1 = __builtin_amdgcn_mfma_f32_16x16x32_bf16(PA1h.b, Bh.b, a1, 0, 0, 0);
                a1 = __builtin_amdgcn_mfma_f32_16x16x32_bf16(PA1h.b, Bl.b, a1, 0, 0, 0);
                a1 = __builtin_amdgcn_mfma_f32_16x16x32_bf16(PA1l.b, Bh.b, a1, 0, 0, 0);
                #pragma unroll
                for (int rr = 0; rr < 4; ++rr) {
                    const int o = (4 + w) * 16 + (lane >> 4) * 4 + rr;
                    out[obase + o * HWp] = a1[rr];
                }
            }
        }
    }
}

// ---------------- launch ----------------

extern "C" void kernel_launch(void* const* d_in, const int* in_sizes, int n_in,
                              void* d_out, int out_size, void* d_ws, size_t ws_size,
                              hipStream_t stream)
{
    const float* x  = (const float*)d_in[0];
    const float* Wv = (const float*)d_in[1];
    const float* bv = (const float*)d_in[2];
    const float* Wq = (const float*)d_in[3];
    const float* bq = (const float*)d_in[4];
    const float* Wk = (const float*)d_in[5];
    const float* bk = (const float*)d_in[6];
    float* out = (float*)d_out;

    float* ws = (float*)d_ws;
    float* Mk   = ws;                 // 9216
    float* Mq   = ws + 9216;
    float* uk   = ws + 18432;
    float* uq   = ws + 18528;
    float* bk2  = ws + 18624;
    float* bq2  = ws + 18720;
    float* scal = ws + 18816;
    unsigned char* wsb = (unsigned char*)d_ws;

    hipLaunchKernelGGL(precompute_mv, dim3(97), dim3(C_), 0, stream,
                       Wq, Wk, bq, bk, Mk, Mq, uk, uq, bk2, bq2, scal);
    hipLaunchKernelGGL(precompute_frags, dim3(120), dim3(64), 0, stream,
                       ws, Wv, wsb);
    hipLaunchKernelGGL(camixer_main, dim3(8 * NWIN * NWIN), dim3(256), 0, stream,
                       x, bv, bk2, bq2, scal,
                       wsb + WS_FRAG_BYTE, wsb + WS_WV_BYTE, out);
}